// Round 1
// baseline (3167.516 us; speedup 1.0000x reference)
//
#include <hip/hip_runtime.h>
#include <cstddef>

typedef unsigned int  uint;
typedef unsigned short ushort_t;
typedef __attribute__((ext_vector_type(8))) short bf16x8;   // 8 bf16 (4 VGPRs) - MFMA A/B frag
typedef __attribute__((ext_vector_type(4))) float f32x4;    // MFMA C/D frag
typedef __attribute__((ext_vector_type(2))) _Float16 h2_t;

// ---------- scalar conversion helpers ----------
__device__ __forceinline__ short f2bs(float x) {            // f32 -> bf16 bits (RNE)
    union { float f; uint u; } v; v.f = x;
    uint r = v.u + 0x7FFF + ((v.u >> 16) & 1);
    return (short)(r >> 16);
}
__device__ __forceinline__ ushort_t f16b(float x) {         // f32 -> f16 bits
    _Float16 h = (_Float16)x; return __builtin_bit_cast(ushort_t, h);
}
__device__ __forceinline__ float h2f(ushort_t u) {
    return (float)__builtin_bit_cast(_Float16, u);
}
__device__ __forceinline__ float fdot2a(uint a, uint b, float c) {
#if __has_builtin(__builtin_amdgcn_fdot2)
    return __builtin_amdgcn_fdot2(__builtin_bit_cast(h2_t, a), __builtin_bit_cast(h2_t, b), c, false);
#else
    h2_t ha = __builtin_bit_cast(h2_t, a), hb = __builtin_bit_cast(h2_t, b);
    return c + (float)ha.x * (float)hb.x + (float)ha.y * (float)hb.y;
#endif
}
__device__ __forceinline__ float fast_sigmoid(float x) {
    float e = __builtin_amdgcn_exp2f(-1.4426950408889634f * x);
    return __builtin_amdgcn_rcpf(1.f + e);
}
__device__ __forceinline__ float fast_tanh(float x) {
    float e = __builtin_amdgcn_exp2f(2.8853900817779268f * x);
    return 1.f - 2.f * __builtin_amdgcn_rcpf(e + 1.f);
}

#define MFMA16(a,b,c) __builtin_amdgcn_mfma_f32_16x16x32_bf16((a),(b),(c),0,0,0)

// ======================= prep kernels =======================
// x f32 [64][1024][256] -> bf16
__global__ void k_prep_x(const float* __restrict__ x, short* __restrict__ xb) {
    int i = (blockIdx.x * 256 + threadIdx.x) * 4;
    float4 v = *(const float4*)&x[i];
    short o[4] = { f2bs(v.x), f2bs(v.y), f2bs(v.z), f2bs(v.w) };
    *(uint2*)&xb[i] = *(uint2*)o;
}
// WkT[n][k] bf16, n in [0,1536): fwd cols then bwd cols
__global__ void k_prep_wk(const float* __restrict__ kf, const float* __restrict__ kb,
                          short* __restrict__ wkt) {
    int n = blockIdx.x, k = threadIdx.x;
    float v = (n < 768) ? kf[k * 768 + n] : kb[k * 768 + (n - 768)];
    wkt[n * 256 + k] = f2bs(v);
}
// recurrent weights packed f16-pairs: Wp[dir][gate][kc][j] (uint4 = k's 8kc..8kc+7)
__global__ void k_prep_wr(const float* __restrict__ wrf, const float* __restrict__ wrb,
                          uint4* __restrict__ wp) {
    int idx = blockIdx.x * 256 + threadIdx.x;          // 49152 total
    int dir = idx / 24576, rem = idx % 24576;
    int g = rem / 8192, rem2 = rem % 8192;
    int kc = rem2 / 256, j = rem2 % 256;
    int col = g * 256 + j;
    const float* w = dir ? wrb : wrf;
    uint c[4];
#pragma unroll
    for (int d = 0; d < 4; d++) {
        int k0 = kc * 8 + d * 2;
        uint lo = f16b(w[k0 * 768 + col]);
        uint hi = f16b(w[(k0 + 1) * 768 + col]);
        c[d] = lo | (hi << 16);
    }
    wp[idx] = make_uint4(c[0], c[1], c[2], c[3]);
}
// WbT_perm[kappa][e] bf16 ; kappa = k*256+n2 ; f = n2*7+k
__global__ void k_prep_wb(const float* __restrict__ wb, short* __restrict__ wbt) {
    int kp = blockIdx.x, e = threadIdx.x;
    int n2 = kp & 255, kk = kp >> 8;
    int f = n2 * 7 + kk;
    wbt[kp * 256 + e] = f2bs(wb[e * 1792 + f]);
}

// ======================= projection GEMM =======================
// [65536 x 256] @ [256 x 1536] -> xp f16 [dir][b][t][768] (+b[0], bwd time-reversed)
__global__ __launch_bounds__(512) void k_proj(const short* __restrict__ xb,
        const short* __restrict__ wkt, const float* __restrict__ gbf,
        const float* __restrict__ gbb, ushort_t* __restrict__ xp) {
    __shared__ union {
        struct { short A[128 * 40]; short B[128 * 40]; } st;
        ushort_t E[128 * 136];
    } u;
    int bid = blockIdx.x;
    int nt = bid % 12, mt = bid / 12;
    int r0 = mt * 128, n0 = nt * 128;
    int tid = threadIdx.x, lane = tid & 63, wid = tid >> 6;
    int wm = wid & 1, wn = wid >> 1;
    int q = lane >> 4, c = lane & 15;
    f32x4 acc[4][2];
#pragma unroll
    for (int mi = 0; mi < 4; mi++)
#pragma unroll
        for (int ni = 0; ni < 2; ni++) acc[mi][ni] = (f32x4){0.f, 0.f, 0.f, 0.f};
    int si = tid >> 2, sp = tid & 3;
    for (int kt = 0; kt < 8; kt++) {
        int k0 = kt * 32;
        *(uint4*)&u.st.A[si * 40 + sp * 8] = *(const uint4*)&xb[(r0 + si) * 256 + k0 + sp * 8];
        *(uint4*)&u.st.B[si * 40 + sp * 8] = *(const uint4*)&wkt[(n0 + si) * 256 + k0 + sp * 8];
        __syncthreads();
        bf16x8 af[4], bfr[2];
#pragma unroll
        for (int mi = 0; mi < 4; mi++) af[mi] = *(bf16x8*)&u.st.A[(wm * 64 + mi * 16 + c) * 40 + q * 8];
#pragma unroll
        for (int ni = 0; ni < 2; ni++) bfr[ni] = *(bf16x8*)&u.st.B[(wn * 32 + ni * 16 + c) * 40 + q * 8];
#pragma unroll
        for (int mi = 0; mi < 4; mi++)
#pragma unroll
            for (int ni = 0; ni < 2; ni++) acc[mi][ni] = MFMA16(af[mi], bfr[ni], acc[mi][ni]);
        __syncthreads();
    }
#pragma unroll
    for (int ni = 0; ni < 2; ni++) {
        int ng = n0 + wn * 32 + ni * 16 + c;
        bool d1 = ng >= 768; int nb = d1 ? ng - 768 : ng;
        float bias = d1 ? gbb[nb] : gbf[nb];
#pragma unroll
        for (int mi = 0; mi < 4; mi++)
#pragma unroll
            for (int v = 0; v < 4; v++) {
                int rl = wm * 64 + mi * 16 + q * 4 + v;
                u.E[rl * 136 + wn * 32 + ni * 16 + c] = f16b(acc[mi][ni][v] + bias);
            }
    }
    __syncthreads();
    {
        int i = tid >> 2, p = tid & 3;
        int r = r0 + i, b = r >> 10, t = r & 1023;
        int ng = n0 + p * 32;
        const ushort_t* src = &u.E[i * 136 + p * 32];
        ushort_t* dst;
        if (ng < 768) dst = xp + (size_t)(b * 1024 + t) * 768 + ng;
        else          dst = xp + 50331648ull + (size_t)(b * 1024 + (1023 - t)) * 768 + (ng - 768);
#pragma unroll
        for (int v = 0; v < 4; v++) *(uint4*)&dst[v * 8] = *(const uint4*)&src[v * 8];
    }
}

// ======================= GRU recurrence =======================
// 128 WGs: one (batch, dir) per CU. Weights resident in VGPRs (384 regs/thread),
// thread j owns triple j (z/r/n cols j, 256+j, 512+j). v_dot2 f16 pairs, f32 accum.
__global__ __launch_bounds__(256, 1) void k_gru(const uint4* __restrict__ wp,
        const ushort_t* __restrict__ xp, const float* __restrict__ gbf,
        const float* __restrict__ gbb, float* __restrict__ cbuf) {
    int wg = blockIdx.x;
    int dir = wg >> 6, b = wg & 63;
    int j = threadIdx.x;
    const uint4* W = wp + dir * 24576 + j;
    uint4 wz[32], wr[32], wn[32];
#pragma unroll
    for (int kc = 0; kc < 32; kc++) {
        wz[kc] = W[kc * 256];
        wr[kc] = W[8192 + kc * 256];
        wn[kc] = W[16384 + kc * 256];
    }
    const float* bs = (dir ? gbb : gbf) + 768 + j;   // b[1] row
    float bz = bs[0], br = bs[256], bn = bs[512];
    const ushort_t* X = xp + ((size_t)dir * 64 + b) * 786432 + j;
    __shared__ uint4 hbuf[32];                       // 256 f16 h values
    ((ushort_t*)hbuf)[j] = 0;
    float h = 0.f;
    __syncthreads();
#pragma unroll 1
    for (int t = 0; t < 1024; t++) {
        ushort_t uz = X[0], ur = X[256], un = X[512];    // prefetch xp for this step
        X += 768;
        float az = 0.f, ar = 0.f, an = 0.f;
#pragma unroll
        for (int kc = 0; kc < 32; kc++) {
            uint4 hc = hbuf[kc];
            uint4 z4 = wz[kc], r4 = wr[kc], n4 = wn[kc];
            az = fdot2a(hc.x, z4.x, az); ar = fdot2a(hc.x, r4.x, ar); an = fdot2a(hc.x, n4.x, an);
            az = fdot2a(hc.y, z4.y, az); ar = fdot2a(hc.y, r4.y, ar); an = fdot2a(hc.y, n4.y, an);
            az = fdot2a(hc.z, z4.z, az); ar = fdot2a(hc.z, r4.z, ar); an = fdot2a(hc.z, n4.z, an);
            az = fdot2a(hc.w, z4.w, az); ar = fdot2a(hc.w, r4.w, ar); an = fdot2a(hc.w, n4.w, an);
        }
        float z = fast_sigmoid(h2f(uz) + az + bz);
        float r = fast_sigmoid(h2f(ur) + ar + br);
        float hh = fast_tanh(h2f(un) + r * (an + bn));
        h = z * h + (1.f - z) * hh;
        __syncthreads();                              // all dot-reads of hbuf done
        ((ushort_t*)hbuf)[j] = f16b(h);
        __syncthreads();
    }
    cbuf[b * 512 + dir * 256 + j] = h;                // c = [hf | hb]
}

// ======================= hyper1: a = c @ Wa =======================
// [64 x 512] @ [512 x 65536] -> a bf16 [64][65536]
__global__ __launch_bounds__(256) void k_hyper1(const float* __restrict__ cbuf,
        const float* __restrict__ Wa, short* __restrict__ aout) {
    __shared__ union {
        struct { short A[64 * 40]; short B[128 * 40]; } st;
        ushort_t E[64 * 136];
    } u;
    int nt = blockIdx.x, n0 = nt * 128;
    int tid = threadIdx.x, lane = tid & 63, wid = tid >> 6;  // 4 waves, wave-tile 64x32
    int q = lane >> 4, c = lane & 15;
    f32x4 acc[4][2];
#pragma unroll
    for (int mi = 0; mi < 4; mi++)
#pragma unroll
        for (int ni = 0; ni < 2; ni++) acc[mi][ni] = (f32x4){0.f, 0.f, 0.f, 0.f};
    for (int kt = 0; kt < 16; kt++) {
        int k0 = kt * 32;
        {   // A 64x32 from cbuf f32 -> bf16
            int i = tid >> 2, p = tid & 3;
            const float* s = &cbuf[i * 512 + k0 + p * 8];
            short tmp[8];
#pragma unroll
            for (int v = 0; v < 8; v++) tmp[v] = f2bs(s[v]);
            *(uint4*)&u.st.A[i * 40 + p * 8] = *(uint4*)tmp;
        }
        {   // B: Wa[k][n] -> LDS [n][k] transposed
            int kk = tid >> 3, nn0 = (tid & 7) * 16;
            const float* s = &Wa[(size_t)(k0 + kk) * 65536 + n0 + nn0];
#pragma unroll
            for (int l = 0; l < 16; l++) u.st.B[(nn0 + l) * 40 + kk] = f2bs(s[l]);
        }
        __syncthreads();
        bf16x8 af[4], bfr[2];
#pragma unroll
        for (int mi = 0; mi < 4; mi++) af[mi] = *(bf16x8*)&u.st.A[(mi * 16 + c) * 40 + q * 8];
#pragma unroll
        for (int ni = 0; ni < 2; ni++) bfr[ni] = *(bf16x8*)&u.st.B[(wid * 32 + ni * 16 + c) * 40 + q * 8];
#pragma unroll
        for (int mi = 0; mi < 4; mi++)
#pragma unroll
            for (int ni = 0; ni < 2; ni++) acc[mi][ni] = MFMA16(af[mi], bfr[ni], acc[mi][ni]);
        __syncthreads();
    }
#pragma unroll
    for (int ni = 0; ni < 2; ni++)
#pragma unroll
        for (int mi = 0; mi < 4; mi++)
#pragma unroll
            for (int v = 0; v < 4; v++)
                u.E[(mi * 16 + q * 4 + v) * 136 + wid * 32 + ni * 16 + c] =
                    (ushort_t)f2bs(acc[mi][ni][v]);
    __syncthreads();
    {
        int i = tid >> 2, p = tid & 3;
        short* dst = aout + (size_t)i * 65536 + n0 + p * 32;
        const ushort_t* src = &u.E[i * 136 + p * 32];
#pragma unroll
        for (int v = 0; v < 4; v++) *(uint4*)&dst[v * 8] = *(const uint4*)&src[v * 8];
    }
}

// ======================= hyper2: fb = a @ WbT_perm =======================
// [16384 x 256] @ [256 x 1792] -> WconvT bf16 [b][co][kappa]
__global__ __launch_bounds__(512) void k_hyper2(const short* __restrict__ a,
        const short* __restrict__ wbt, short* __restrict__ wc) {
    __shared__ union {
        struct { short A[128 * 40]; short B[128 * 40]; } st;
        ushort_t E[128 * 136];
    } u;
    int bid = blockIdx.x;
    int nt = bid % 14, mt = bid / 14;
    int r0 = mt * 128, n0 = nt * 128;
    int tid = threadIdx.x, lane = tid & 63, wid = tid >> 6;
    int wm = wid & 1, wn = wid >> 1;
    int q = lane >> 4, c = lane & 15;
    f32x4 acc[4][2];
#pragma unroll
    for (int mi = 0; mi < 4; mi++)
#pragma unroll
        for (int ni = 0; ni < 2; ni++) acc[mi][ni] = (f32x4){0.f, 0.f, 0.f, 0.f};
    int si = tid >> 2, sp = tid & 3;
    for (int kt = 0; kt < 8; kt++) {
        int k0 = kt * 32;
        *(uint4*)&u.st.A[si * 40 + sp * 8] = *(const uint4*)&a[(r0 + si) * 256 + k0 + sp * 8];
        *(uint4*)&u.st.B[si * 40 + sp * 8] = *(const uint4*)&wbt[(n0 + si) * 256 + k0 + sp * 8];
        __syncthreads();
        bf16x8 af[4], bfr[2];
#pragma unroll
        for (int mi = 0; mi < 4; mi++) af[mi] = *(bf16x8*)&u.st.A[(wm * 64 + mi * 16 + c) * 40 + q * 8];
#pragma unroll
        for (int ni = 0; ni < 2; ni++) bfr[ni] = *(bf16x8*)&u.st.B[(wn * 32 + ni * 16 + c) * 40 + q * 8];
#pragma unroll
        for (int mi = 0; mi < 4; mi++)
#pragma unroll
            for (int ni = 0; ni < 2; ni++) acc[mi][ni] = MFMA16(af[mi], bfr[ni], acc[mi][ni]);
        __syncthreads();
    }
#pragma unroll
    for (int ni = 0; ni < 2; ni++)
#pragma unroll
        for (int mi = 0; mi < 4; mi++)
#pragma unroll
            for (int v = 0; v < 4; v++)
                u.E[(wm * 64 + mi * 16 + q * 4 + v) * 136 + wn * 32 + ni * 16 + c] =
                    (ushort_t)f2bs(acc[mi][ni][v]);
    __syncthreads();
    {
        int i = tid >> 2, p = tid & 3;
        int r = r0 + i, b = r >> 8, co = r & 255;
        short* dst = wc + (size_t)(b * 256 + co) * 1792 + n0 + p * 32;
        const ushort_t* src = &u.E[i * 136 + p * 32];
#pragma unroll
        for (int v = 0; v < 4; v++) *(uint4*)&dst[v * 8] = *(const uint4*)&src[v * 8];
    }
}

// ======================= per-sample conv + relu + maxpool =======================
// per b: [1024 x 1792] @ [1792 x 256]; A[s][kappa=k*256+ci] = x[b][s+k-3][ci]
__global__ __launch_bounds__(512) void k_conv(const short* __restrict__ xb,
        const short* __restrict__ wc, const float* __restrict__ cbias,
        float* __restrict__ out) {
    __shared__ union {
        struct { short A[128 * 72]; short B[256 * 72]; } st;
        ushort_t Y[128 * 256];
    } u;
    int bid = blockIdx.x;
    int bb = bid & 63, mt = bid >> 6;        // bid = mt*64+b : all mt of b on same XCD
    int s0 = mt * 126, p0 = mt * 42;
    int tid = threadIdx.x, lane = tid & 63, wid = tid >> 6;
    int wm = wid & 1, wn = wid >> 1;
    int q = lane >> 4, c = lane & 15;
    const short* xbb = xb + (size_t)bb * 262144;
    const short* wcb = wc + (size_t)bb * 458752;
    f32x4 acc[4][4];
#pragma unroll
    for (int mi = 0; mi < 4; mi++)
#pragma unroll
        for (int ni = 0; ni < 4; ni++) acc[mi][ni] = (f32x4){0.f, 0.f, 0.f, 0.f};
    for (int kc = 0; kc < 28; kc++) {
        int k = kc >> 2, c0 = (kc & 3) * 64;
        {   // A stage 128 x 64 (shifted x rows, zero-padded)
            int i = tid >> 2, p = tid & 3;
            int rs = s0 + i + k - 3;
            uint4 v0 = {0, 0, 0, 0}, v1 = {0, 0, 0, 0};
            if (rs >= 0 && rs < 1024) {
                const uint4* s = (const uint4*)&xbb[rs * 256 + c0 + p * 16];
                v0 = s[0]; v1 = s[1];
            }
            uint4* d = (uint4*)&u.st.A[i * 72 + p * 16];
            d[0] = v0; d[1] = v1;
        }
        {   // B stage 256co x 64kappa from WconvT[b][co][kappa]
            int co = tid >> 1, p = tid & 1;
            const uint4* s = (const uint4*)&wcb[co * 1792 + kc * 64 + p * 32];
            uint4* d = (uint4*)&u.st.B[co * 72 + p * 32];
            d[0] = s[0]; d[1] = s[1]; d[2] = s[2]; d[3] = s[3];
        }
        __syncthreads();
        bf16x8 af[4][2], bfr[4][2];
#pragma unroll
        for (int mi = 0; mi < 4; mi++)
#pragma unroll
            for (int kt = 0; kt < 2; kt++)
                af[mi][kt] = *(bf16x8*)&u.st.A[(wm * 64 + mi * 16 + c) * 72 + kt * 32 + q * 8];
#pragma unroll
        for (int ni = 0; ni < 4; ni++)
#pragma unroll
            for (int kt = 0; kt < 2; kt++)
                bfr[ni][kt] = *(bf16x8*)&u.st.B[(wn * 64 + ni * 16 + c) * 72 + kt * 32 + q * 8];
#pragma unroll
        for (int kt = 0; kt < 2; kt++)
#pragma unroll
            for (int mi = 0; mi < 4; mi++)
#pragma unroll
                for (int ni = 0; ni < 4; ni++)
                    acc[mi][ni] = MFMA16(af[mi][kt], bfr[ni][kt], acc[mi][ni]);
        __syncthreads();
    }
    // epilogue: +bias, relu, stage f16 y-tile
#pragma unroll
    for (int ni = 0; ni < 4; ni++) {
        int cg = wn * 64 + ni * 16 + c;
        float bias = cbias[cg];
#pragma unroll
        for (int mi = 0; mi < 4; mi++)
#pragma unroll
            for (int v = 0; v < 4; v++) {
                int rl = wm * 64 + mi * 16 + q * 4 + v;
                float val = acc[mi][ni][v] + bias;
                u.Y[rl * 256 + cg] = f16b(fmaxf(val, 0.f));
            }
    }
    __syncthreads();
    // maxpool(3): 42 pools x 256 channels
    for (int it = 0; it < 21; it++) {
        int idx = it * 512 + tid;
        int pp = idx >> 8, co = idx & 255;
        int p = p0 + pp;
        if (p < 341) {
            float a0 = h2f(u.Y[(3 * pp) * 256 + co]);
            float a1 = h2f(u.Y[(3 * pp + 1) * 256 + co]);
            float a2 = h2f(u.Y[(3 * pp + 2) * 256 + co]);
            out[(size_t)(bb * 341 + p) * 256 + co] = fmaxf(fmaxf(a0, a1), a2);
        }
    }
}

// ======================= launcher =======================
extern "C" void kernel_launch(void* const* d_in, const int* in_sizes, int n_in,
                              void* d_out, int out_size, void* d_ws, size_t ws_size,
                              hipStream_t stream) {
    const float* x    = (const float*)d_in[0];
    const float* gkf  = (const float*)d_in[2];
    const float* grf  = (const float*)d_in[3];
    const float* gbf  = (const float*)d_in[4];
    const float* gkb  = (const float*)d_in[5];
    const float* grb  = (const float*)d_in[6];
    const float* gbb  = (const float*)d_in[7];
    const float* Wa   = (const float*)d_in[8];
    const float* Wb   = (const float*)d_in[9];
    const float* cbias= (const float*)d_in[10];
    float* out = (float*)d_out;
    char* ws = (char*)d_ws;

    short*    xb   = (short*)(ws);                      // 33,554,432 B
    ushort_t* xp   = (ushort_t*)(ws + 33554432);        // 201,326,592 B (f+b, f16)
    short*    wkt  = (short*)(ws + 234881024);          // 786,432 B
    uint4*    wp   = (uint4*)(ws + 235667456);          // 786,432 B
    short*    wbt  = (short*)(ws + 236453888);          // 917,504 B
    float*    cbuf = (float*)(ws + 237371392);          // 131,072 B
    short*    aout = (short*)(ws + 237502464);          // 8,388,608 B
    short*    wc   = (short*)(ws + 245891072);          // 58,720,256 B  (end ~304.6 MB)

    hipLaunchKernelGGL(k_prep_x,  dim3(16384), dim3(256), 0, stream, x, xb);
    hipLaunchKernelGGL(k_prep_wk, dim3(1536),  dim3(256), 0, stream, gkf, gkb, wkt);
    hipLaunchKernelGGL(k_prep_wr, dim3(192),   dim3(256), 0, stream, grf, grb, wp);
    hipLaunchKernelGGL(k_prep_wb, dim3(1792),  dim3(256), 0, stream, Wb, wbt);
    hipLaunchKernelGGL(k_proj,    dim3(6144),  dim3(512), 0, stream, xb, wkt, gbf, gbb, xp);
    hipLaunchKernelGGL(k_gru,     dim3(128),   dim3(256), 0, stream, wp, xp, gbf, gbb, cbuf);
    hipLaunchKernelGGL(k_hyper1,  dim3(512),   dim3(256), 0, stream, cbuf, Wa, aout);
    hipLaunchKernelGGL(k_hyper2,  dim3(1792),  dim3(512), 0, stream, aout, wbt, wc);
    hipLaunchKernelGGL(k_conv,    dim3(576),   dim3(512), 0, stream, xb, wc, cbias, out);
}

// Round 2
// 1574.937 us; speedup vs baseline: 2.0112x; 2.0112x over previous
//
#include <hip/hip_runtime.h>
#include <cstddef>

typedef unsigned int  uint;
typedef unsigned short ushort_t;
typedef __attribute__((ext_vector_type(8))) short bf16x8;   // 8 bf16 (4 VGPRs) - MFMA A/B frag
typedef __attribute__((ext_vector_type(4))) float f32x4;    // MFMA C/D frag
typedef __attribute__((ext_vector_type(2))) _Float16 h2_t;

// ---------- scalar conversion helpers ----------
__device__ __forceinline__ short f2bs(float x) {            // f32 -> bf16 bits (RNE)
    union { float f; uint u; } v; v.f = x;
    uint r = v.u + 0x7FFF + ((v.u >> 16) & 1);
    return (short)(r >> 16);
}
__device__ __forceinline__ ushort_t f16b(float x) {         // f32 -> f16 bits
    _Float16 h = (_Float16)x; return __builtin_bit_cast(ushort_t, h);
}
__device__ __forceinline__ float h2f(ushort_t u) {
    return (float)__builtin_bit_cast(_Float16, u);
}
__device__ __forceinline__ float fdot2a(uint a, uint b, float c) {
#if __has_builtin(__builtin_amdgcn_fdot2)
    return __builtin_amdgcn_fdot2(__builtin_bit_cast(h2_t, a), __builtin_bit_cast(h2_t, b), c, false);
#else
    h2_t ha = __builtin_bit_cast(h2_t, a), hb = __builtin_bit_cast(h2_t, b);
    return c + (float)ha.x * (float)hb.x + (float)ha.y * (float)hb.y;
#endif
}
__device__ __forceinline__ float fast_sigmoid(float x) {
    float e = __builtin_amdgcn_exp2f(-1.4426950408889634f * x);
    return __builtin_amdgcn_rcpf(1.f + e);
}
__device__ __forceinline__ float fast_tanh(float x) {
    float e = __builtin_amdgcn_exp2f(2.8853900817779268f * x);
    return 1.f - 2.f * __builtin_amdgcn_rcpf(e + 1.f);
}

#define MFMA16(a,b,c) __builtin_amdgcn_mfma_f32_16x16x32_bf16((a),(b),(c),0,0,0)

// ======================= prep kernels =======================
// x f32 [64][1024][256] -> bf16
__global__ void k_prep_x(const float* __restrict__ x, short* __restrict__ xb) {
    int i = (blockIdx.x * 256 + threadIdx.x) * 4;
    float4 v = *(const float4*)&x[i];
    short o[4] = { f2bs(v.x), f2bs(v.y), f2bs(v.z), f2bs(v.w) };
    *(uint2*)&xb[i] = *(uint2*)o;
}
// WkT[n][k] bf16, n in [0,1536): fwd cols then bwd cols
__global__ void k_prep_wk(const float* __restrict__ kf, const float* __restrict__ kb,
                          short* __restrict__ wkt) {
    int n = blockIdx.x, k = threadIdx.x;
    float v = (n < 768) ? kf[k * 768 + n] : kb[k * 768 + (n - 768)];
    wkt[n * 256 + k] = f2bs(v);
}
// recurrent weights packed f16-pairs: Wp[dir][gate][kc][j] (uint4 = k's 8kc..8kc+7)
__global__ void k_prep_wr(const float* __restrict__ wrf, const float* __restrict__ wrb,
                          uint4* __restrict__ wp) {
    int idx = blockIdx.x * 256 + threadIdx.x;          // 49152 total
    int dir = idx / 24576, rem = idx % 24576;
    int g = rem / 8192, rem2 = rem % 8192;
    int kc = rem2 / 256, j = rem2 % 256;
    int col = g * 256 + j;
    const float* w = dir ? wrb : wrf;
    uint c[4];
#pragma unroll
    for (int d = 0; d < 4; d++) {
        int k0 = kc * 8 + d * 2;
        uint lo = f16b(w[k0 * 768 + col]);
        uint hi = f16b(w[(k0 + 1) * 768 + col]);
        c[d] = lo | (hi << 16);
    }
    wp[idx] = make_uint4(c[0], c[1], c[2], c[3]);
}
// WbT_perm[kappa][e] bf16 ; kappa = k*256+n2 ; f = n2*7+k
__global__ void k_prep_wb(const float* __restrict__ wb, short* __restrict__ wbt) {
    int kp = blockIdx.x, e = threadIdx.x;
    int n2 = kp & 255, kk = kp >> 8;
    int f = n2 * 7 + kk;
    wbt[kp * 256 + e] = f2bs(wb[e * 1792 + f]);
}

// ======================= projection GEMM =======================
// [65536 x 256] @ [256 x 1536] -> xp f16 [dir][b][t][768] (+b[0], bwd time-reversed)
__global__ __launch_bounds__(512) void k_proj(const short* __restrict__ xb,
        const short* __restrict__ wkt, const float* __restrict__ gbf,
        const float* __restrict__ gbb, ushort_t* __restrict__ xp) {
    __shared__ union {
        struct { short A[128 * 40]; short B[128 * 40]; } st;
        ushort_t E[128 * 136];
    } u;
    int bid = blockIdx.x;
    int nt = bid % 12, mt = bid / 12;
    int r0 = mt * 128, n0 = nt * 128;
    int tid = threadIdx.x, lane = tid & 63, wid = tid >> 6;
    int wm = wid & 1, wn = wid >> 1;
    int q = lane >> 4, c = lane & 15;
    f32x4 acc[4][2];
#pragma unroll
    for (int mi = 0; mi < 4; mi++)
#pragma unroll
        for (int ni = 0; ni < 2; ni++) acc[mi][ni] = (f32x4){0.f, 0.f, 0.f, 0.f};
    int si = tid >> 2, sp = tid & 3;
    for (int kt = 0; kt < 8; kt++) {
        int k0 = kt * 32;
        *(uint4*)&u.st.A[si * 40 + sp * 8] = *(const uint4*)&xb[(r0 + si) * 256 + k0 + sp * 8];
        *(uint4*)&u.st.B[si * 40 + sp * 8] = *(const uint4*)&wkt[(n0 + si) * 256 + k0 + sp * 8];
        __syncthreads();
        bf16x8 af[4], bfr[2];
#pragma unroll
        for (int mi = 0; mi < 4; mi++) af[mi] = *(bf16x8*)&u.st.A[(wm * 64 + mi * 16 + c) * 40 + q * 8];
#pragma unroll
        for (int ni = 0; ni < 2; ni++) bfr[ni] = *(bf16x8*)&u.st.B[(wn * 32 + ni * 16 + c) * 40 + q * 8];
#pragma unroll
        for (int mi = 0; mi < 4; mi++)
#pragma unroll
            for (int ni = 0; ni < 2; ni++) acc[mi][ni] = MFMA16(af[mi], bfr[ni], acc[mi][ni]);
        __syncthreads();
    }
#pragma unroll
    for (int ni = 0; ni < 2; ni++) {
        int ng = n0 + wn * 32 + ni * 16 + c;
        bool d1 = ng >= 768; int nb = d1 ? ng - 768 : ng;
        float bias = d1 ? gbb[nb] : gbf[nb];
#pragma unroll
        for (int mi = 0; mi < 4; mi++)
#pragma unroll
            for (int v = 0; v < 4; v++) {
                int rl = wm * 64 + mi * 16 + q * 4 + v;
                u.E[rl * 136 + wn * 32 + ni * 16 + c] = f16b(acc[mi][ni][v] + bias);
            }
    }
    __syncthreads();
    {
        int i = tid >> 2, p = tid & 3;
        int r = r0 + i, b = r >> 10, t = r & 1023;
        int ng = n0 + p * 32;
        const ushort_t* src = &u.E[i * 136 + p * 32];
        ushort_t* dst;
        if (ng < 768) dst = xp + (size_t)(b * 1024 + t) * 768 + ng;
        else          dst = xp + 50331648ull + (size_t)(b * 1024 + (1023 - t)) * 768 + (ng - 768);
#pragma unroll
        for (int v = 0; v < 4; v++) *(uint4*)&dst[v * 8] = *(const uint4*)&src[v * 8];
    }
}

// ======================= GRU recurrence =======================
// 128 WGs x 512 thr: one (batch, dir) per CU, 8 waves (2/SIMD) for latency hiding.
// K-dim split in half WITHIN the wave: lanes l and l^32 share output triple j,
// each holds 16 uint4 x 3 gates = 192 weight VGPRs (fits 256-cap at 2 waves/SIMD,
// no AGPR shuttling). Reduction = one shfl_xor(32). Double-buffered hbuf ->
// single barrier per step. v_dot2 f16 pairs, f32 accum.
__global__ __launch_bounds__(512, 2) void k_gru(const uint4* __restrict__ wp,
        const ushort_t* __restrict__ xp, const float* __restrict__ gbf,
        const float* __restrict__ gbb, float* __restrict__ cbuf) {
    int wg = blockIdx.x;
    int dir = wg >> 6, b = wg & 63;
    int tid = threadIdx.x;
    int lane = tid & 63, w = tid >> 6;
    int half = lane >> 5;
    int j = w * 32 + (lane & 31);
    const uint4* W = wp + dir * 24576 + half * 4096 + j;   // half*16 kc-rows
    uint4 wz[16], wr[16], wn[16];
#pragma unroll
    for (int kc = 0; kc < 16; kc++) {
        wz[kc] = W[kc * 256];
        wr[kc] = W[8192 + kc * 256];
        wn[kc] = W[16384 + kc * 256];
    }
    __shared__ uint4 hbuf[2][32];
    float bz = 0.f, br = 0.f, bn = 0.f, h = 0.f;
    ushort_t uz = 0, ur = 0, un = 0;
    const ushort_t* Xn = xp;
    if (half == 0) {
        const float* bs = (dir ? gbb : gbf) + 768 + j;   // b[1] row
        bz = bs[0]; br = bs[256]; bn = bs[512];
        const ushort_t* X = xp + ((size_t)dir * 64 + b) * 786432 + j;
        uz = X[0]; ur = X[256]; un = X[512];
        Xn = X + 768;
    }
    if (tid < 32) hbuf[0][tid] = (uint4){0, 0, 0, 0};
    __syncthreads();
#pragma unroll 1
    for (int tt = 0; tt < 1024; tt++) {
        const uint4* hb = &hbuf[tt & 1][half * 16];
        ushort_t nz = 0, nr = 0, nn = 0;
        if (half == 0) {                                  // prefetch step tt+1
            nz = Xn[0]; nr = Xn[256]; nn = Xn[512]; Xn += 768;
        }
        float az = 0.f, ar = 0.f, an = 0.f;
#pragma unroll
        for (int kc = 0; kc < 16; kc++) {
            uint4 hc = hb[kc];
            uint4 z4 = wz[kc], r4 = wr[kc], n4 = wn[kc];
            az = fdot2a(hc.x, z4.x, az); ar = fdot2a(hc.x, r4.x, ar); an = fdot2a(hc.x, n4.x, an);
            az = fdot2a(hc.y, z4.y, az); ar = fdot2a(hc.y, r4.y, ar); an = fdot2a(hc.y, n4.y, an);
            az = fdot2a(hc.z, z4.z, az); ar = fdot2a(hc.z, r4.z, ar); an = fdot2a(hc.z, n4.z, an);
            az = fdot2a(hc.w, z4.w, az); ar = fdot2a(hc.w, r4.w, ar); an = fdot2a(hc.w, n4.w, an);
        }
        float azo = __shfl_xor(az, 32, 64);
        float aro = __shfl_xor(ar, 32, 64);
        float ano = __shfl_xor(an, 32, 64);
        if (half == 0) {
            az += azo; ar += aro; an += ano;
            float z = fast_sigmoid(h2f(uz) + az + bz);
            float r = fast_sigmoid(h2f(ur) + ar + br);
            float hh = fast_tanh(h2f(un) + r * (an + bn));
            h = z * h + (1.f - z) * hh;
            uz = nz; ur = nr; un = nn;
            ((ushort_t*)&hbuf[(tt & 1) ^ 1][0])[j] = f16b(h);
        }
        __syncthreads();
    }
    if (half == 0) cbuf[b * 512 + dir * 256 + j] = h;     // c = [hf | hb]
}

// ======================= hyper1: a = c @ Wa =======================
// [64 x 512] @ [512 x 65536] -> a bf16 [64][65536]
__global__ __launch_bounds__(256) void k_hyper1(const float* __restrict__ cbuf,
        const float* __restrict__ Wa, short* __restrict__ aout) {
    __shared__ union {
        struct { short A[64 * 40]; short B[128 * 40]; } st;
        ushort_t E[64 * 136];
    } u;
    int nt = blockIdx.x, n0 = nt * 128;
    int tid = threadIdx.x, lane = tid & 63, wid = tid >> 6;  // 4 waves, wave-tile 64x32
    int q = lane >> 4, c = lane & 15;
    f32x4 acc[4][2];
#pragma unroll
    for (int mi = 0; mi < 4; mi++)
#pragma unroll
        for (int ni = 0; ni < 2; ni++) acc[mi][ni] = (f32x4){0.f, 0.f, 0.f, 0.f};
    for (int kt = 0; kt < 16; kt++) {
        int k0 = kt * 32;
        {   // A 64x32 from cbuf f32 -> bf16
            int i = tid >> 2, p = tid & 3;
            const float* s = &cbuf[i * 512 + k0 + p * 8];
            short tmp[8];
#pragma unroll
            for (int v = 0; v < 8; v++) tmp[v] = f2bs(s[v]);
            *(uint4*)&u.st.A[i * 40 + p * 8] = *(uint4*)tmp;
        }
        {   // B: Wa[k][n] -> LDS [n][k] transposed
            int kk = tid >> 3, nn0 = (tid & 7) * 16;
            const float* s = &Wa[(size_t)(k0 + kk) * 65536 + n0 + nn0];
#pragma unroll
            for (int l = 0; l < 16; l++) u.st.B[(nn0 + l) * 40 + kk] = f2bs(s[l]);
        }
        __syncthreads();
        bf16x8 af[4], bfr[2];
#pragma unroll
        for (int mi = 0; mi < 4; mi++) af[mi] = *(bf16x8*)&u.st.A[(mi * 16 + c) * 40 + q * 8];
#pragma unroll
        for (int ni = 0; ni < 2; ni++) bfr[ni] = *(bf16x8*)&u.st.B[(wid * 32 + ni * 16 + c) * 40 + q * 8];
#pragma unroll
        for (int mi = 0; mi < 4; mi++)
#pragma unroll
            for (int ni = 0; ni < 2; ni++) acc[mi][ni] = MFMA16(af[mi], bfr[ni], acc[mi][ni]);
        __syncthreads();
    }
#pragma unroll
    for (int ni = 0; ni < 2; ni++)
#pragma unroll
        for (int mi = 0; mi < 4; mi++)
#pragma unroll
            for (int v = 0; v < 4; v++)
                u.E[(mi * 16 + q * 4 + v) * 136 + wid * 32 + ni * 16 + c] =
                    (ushort_t)f2bs(acc[mi][ni][v]);
    __syncthreads();
    {
        int i = tid >> 2, p = tid & 3;
        short* dst = aout + (size_t)i * 65536 + n0 + p * 32;
        const ushort_t* src = &u.E[i * 136 + p * 32];
#pragma unroll
        for (int v = 0; v < 4; v++) *(uint4*)&dst[v * 8] = *(const uint4*)&src[v * 8];
    }
}

// ======================= hyper2: fb = a @ WbT_perm =======================
// [16384 x 256] @ [256 x 1792] -> WconvT bf16 [b][co][kappa]
__global__ __launch_bounds__(512) void k_hyper2(const short* __restrict__ a,
        const short* __restrict__ wbt, short* __restrict__ wc) {
    __shared__ union {
        struct { short A[128 * 40]; short B[128 * 40]; } st;
        ushort_t E[128 * 136];
    } u;
    int bid = blockIdx.x;
    int nt = bid % 14, mt = bid / 14;
    int r0 = mt * 128, n0 = nt * 128;
    int tid = threadIdx.x, lane = tid & 63, wid = tid >> 6;
    int wm = wid & 1, wn = wid >> 1;
    int q = lane >> 4, c = lane & 15;
    f32x4 acc[4][2];
#pragma unroll
    for (int mi = 0; mi < 4; mi++)
#pragma unroll
        for (int ni = 0; ni < 2; ni++) acc[mi][ni] = (f32x4){0.f, 0.f, 0.f, 0.f};
    int si = tid >> 2, sp = tid & 3;
    for (int kt = 0; kt < 8; kt++) {
        int k0 = kt * 32;
        *(uint4*)&u.st.A[si * 40 + sp * 8] = *(const uint4*)&a[(r0 + si) * 256 + k0 + sp * 8];
        *(uint4*)&u.st.B[si * 40 + sp * 8] = *(const uint4*)&wbt[(n0 + si) * 256 + k0 + sp * 8];
        __syncthreads();
        bf16x8 af[4], bfr[2];
#pragma unroll
        for (int mi = 0; mi < 4; mi++) af[mi] = *(bf16x8*)&u.st.A[(wm * 64 + mi * 16 + c) * 40 + q * 8];
#pragma unroll
        for (int ni = 0; ni < 2; ni++) bfr[ni] = *(bf16x8*)&u.st.B[(wn * 32 + ni * 16 + c) * 40 + q * 8];
#pragma unroll
        for (int mi = 0; mi < 4; mi++)
#pragma unroll
            for (int ni = 0; ni < 2; ni++) acc[mi][ni] = MFMA16(af[mi], bfr[ni], acc[mi][ni]);
        __syncthreads();
    }
#pragma unroll
    for (int ni = 0; ni < 2; ni++)
#pragma unroll
        for (int mi = 0; mi < 4; mi++)
#pragma unroll
            for (int v = 0; v < 4; v++)
                u.E[(wm * 64 + mi * 16 + q * 4 + v) * 136 + wn * 32 + ni * 16 + c] =
                    (ushort_t)f2bs(acc[mi][ni][v]);
    __syncthreads();
    {
        int i = tid >> 2, p = tid & 3;
        int r = r0 + i, b = r >> 8, co = r & 255;
        short* dst = wc + (size_t)(b * 256 + co) * 1792 + n0 + p * 32;
        const ushort_t* src = &u.E[i * 136 + p * 32];
#pragma unroll
        for (int v = 0; v < 4; v++) *(uint4*)&dst[v * 8] = *(const uint4*)&src[v * 8];
    }
}

// ======================= per-sample conv + relu + maxpool =======================
// per b: [1024 x 1792] @ [1792 x 256]; A[s][kappa=k*256+ci] = x[b][s+k-3][ci]
__global__ __launch_bounds__(512) void k_conv(const short* __restrict__ xb,
        const short* __restrict__ wc, const float* __restrict__ cbias,
        float* __restrict__ out) {
    __shared__ union {
        struct { short A[128 * 72]; short B[256 * 72]; } st;
        ushort_t Y[128 * 256];
    } u;
    int bid = blockIdx.x;
    int bb = bid & 63, mt = bid >> 6;        // bid = mt*64+b : all mt of b on same XCD
    int s0 = mt * 126, p0 = mt * 42;
    int tid = threadIdx.x, lane = tid & 63, wid = tid >> 6;
    int wm = wid & 1, wn = wid >> 1;
    int q = lane >> 4, c = lane & 15;
    const short* xbb = xb + (size_t)bb * 262144;
    const short* wcb = wc + (size_t)bb * 458752;
    f32x4 acc[4][4];
#pragma unroll
    for (int mi = 0; mi < 4; mi++)
#pragma unroll
        for (int ni = 0; ni < 4; ni++) acc[mi][ni] = (f32x4){0.f, 0.f, 0.f, 0.f};
    for (int kc = 0; kc < 28; kc++) {
        int k = kc >> 2, c0 = (kc & 3) * 64;
        {   // A stage 128 x 64 (shifted x rows, zero-padded)
            int i = tid >> 2, p = tid & 3;
            int rs = s0 + i + k - 3;
            uint4 v0 = {0, 0, 0, 0}, v1 = {0, 0, 0, 0};
            if (rs >= 0 && rs < 1024) {
                const uint4* s = (const uint4*)&xbb[rs * 256 + c0 + p * 16];
                v0 = s[0]; v1 = s[1];
            }
            uint4* d = (uint4*)&u.st.A[i * 72 + p * 16];
            d[0] = v0; d[1] = v1;
        }
        {   // B stage 256co x 64kappa from WconvT[b][co][kappa]
            int co = tid >> 1, p = tid & 1;
            const uint4* s = (const uint4*)&wcb[co * 1792 + kc * 64 + p * 32];
            uint4* d = (uint4*)&u.st.B[co * 72 + p * 32];
            d[0] = s[0]; d[1] = s[1]; d[2] = s[2]; d[3] = s[3];
        }
        __syncthreads();
        bf16x8 af[4][2], bfr[4][2];
#pragma unroll
        for (int mi = 0; mi < 4; mi++)
#pragma unroll
            for (int kt = 0; kt < 2; kt++)
                af[mi][kt] = *(bf16x8*)&u.st.A[(wm * 64 + mi * 16 + c) * 72 + kt * 32 + q * 8];
#pragma unroll
        for (int ni = 0; ni < 4; ni++)
#pragma unroll
            for (int kt = 0; kt < 2; kt++)
                bfr[ni][kt] = *(bf16x8*)&u.st.B[(wn * 64 + ni * 16 + c) * 72 + kt * 32 + q * 8];
#pragma unroll
        for (int kt = 0; kt < 2; kt++)
#pragma unroll
            for (int mi = 0; mi < 4; mi++)
#pragma unroll
                for (int ni = 0; ni < 4; ni++)
                    acc[mi][ni] = MFMA16(af[mi][kt], bfr[ni][kt], acc[mi][ni]);
        __syncthreads();
    }
    // epilogue: +bias, relu, stage f16 y-tile
#pragma unroll
    for (int ni = 0; ni < 4; ni++) {
        int cg = wn * 64 + ni * 16 + c;
        float bias = cbias[cg];
#pragma unroll
        for (int mi = 0; mi < 4; mi++)
#pragma unroll
            for (int v = 0; v < 4; v++) {
                int rl = wm * 64 + mi * 16 + q * 4 + v;
                float val = acc[mi][ni][v] + bias;
                u.Y[rl * 256 + cg] = f16b(fmaxf(val, 0.f));
            }
    }
    __syncthreads();
    // maxpool(3): 42 pools x 256 channels
    for (int it = 0; it < 21; it++) {
        int idx = it * 512 + tid;
        int pp = idx >> 8, co = idx & 255;
        int p = p0 + pp;
        if (p < 341) {
            float a0 = h2f(u.Y[(3 * pp) * 256 + co]);
            float a1 = h2f(u.Y[(3 * pp + 1) * 256 + co]);
            float a2 = h2f(u.Y[(3 * pp + 2) * 256 + co]);
            out[(size_t)(bb * 341 + p) * 256 + co] = fmaxf(fmaxf(a0, a1), a2);
        }
    }
}

// ======================= launcher =======================
extern "C" void kernel_launch(void* const* d_in, const int* in_sizes, int n_in,
                              void* d_out, int out_size, void* d_ws, size_t ws_size,
                              hipStream_t stream) {
    const float* x    = (const float*)d_in[0];
    const float* gkf  = (const float*)d_in[2];
    const float* grf  = (const float*)d_in[3];
    const float* gbf  = (const float*)d_in[4];
    const float* gkb  = (const float*)d_in[5];
    const float* grb  = (const float*)d_in[6];
    const float* gbb  = (const float*)d_in[7];
    const float* Wa   = (const float*)d_in[8];
    const float* Wb   = (const float*)d_in[9];
    const float* cbias= (const float*)d_in[10];
    float* out = (float*)d_out;
    char* ws = (char*)d_ws;

    short*    xb   = (short*)(ws);                      // 33,554,432 B
    ushort_t* xp   = (ushort_t*)(ws + 33554432);        // 201,326,592 B (f+b, f16)
    short*    wkt  = (short*)(ws + 234881024);          // 786,432 B
    uint4*    wp   = (uint4*)(ws + 235667456);          // 786,432 B
    short*    wbt  = (short*)(ws + 236453888);          // 917,504 B
    float*    cbuf = (float*)(ws + 237371392);          // 131,072 B
    short*    aout = (short*)(ws + 237502464);          // 8,388,608 B
    short*    wc   = (short*)(ws + 245891072);          // 58,720,256 B  (end ~304.6 MB)

    hipLaunchKernelGGL(k_prep_x,  dim3(16384), dim3(256), 0, stream, x, xb);
    hipLaunchKernelGGL(k_prep_wk, dim3(1536),  dim3(256), 0, stream, gkf, gkb, wkt);
    hipLaunchKernelGGL(k_prep_wr, dim3(192),   dim3(256), 0, stream, grf, grb, wp);
    hipLaunchKernelGGL(k_prep_wb, dim3(1792),  dim3(256), 0, stream, Wb, wbt);
    hipLaunchKernelGGL(k_proj,    dim3(6144),  dim3(512), 0, stream, xb, wkt, gbf, gbb, xp);
    hipLaunchKernelGGL(k_gru,     dim3(128),   dim3(512), 0, stream, wp, xp, gbf, gbb, cbuf);
    hipLaunchKernelGGL(k_hyper1,  dim3(512),   dim3(256), 0, stream, cbuf, Wa, aout);
    hipLaunchKernelGGL(k_hyper2,  dim3(1792),  dim3(512), 0, stream, aout, wbt, wc);
    hipLaunchKernelGGL(k_conv,    dim3(576),   dim3(512), 0, stream, xb, wc, cbias, out);
}

// Round 3
// 1565.596 us; speedup vs baseline: 2.0232x; 1.0060x over previous
//
#include <hip/hip_runtime.h>
#include <cstddef>

typedef unsigned int  uint;
typedef unsigned short ushort_t;
typedef __attribute__((ext_vector_type(8))) short bf16x8;   // 8 bf16 (4 VGPRs) - MFMA A/B frag
typedef __attribute__((ext_vector_type(4))) float f32x4;    // MFMA C/D frag
typedef __attribute__((ext_vector_type(2))) _Float16 h2_t;

// ---------- scalar conversion helpers ----------
__device__ __forceinline__ short f2bs(float x) {            // f32 -> bf16 bits (RNE)
    union { float f; uint u; } v; v.f = x;
    uint r = v.u + 0x7FFF + ((v.u >> 16) & 1);
    return (short)(r >> 16);
}
__device__ __forceinline__ ushort_t f16b(float x) {         // f32 -> f16 bits
    _Float16 h = (_Float16)x; return __builtin_bit_cast(ushort_t, h);
}
__device__ __forceinline__ float h2f(ushort_t u) {
    return (float)__builtin_bit_cast(_Float16, u);
}
__device__ __forceinline__ float fdot2a(uint a, uint b, float c) {
#if __has_builtin(__builtin_amdgcn_fdot2)
    return __builtin_amdgcn_fdot2(__builtin_bit_cast(h2_t, a), __builtin_bit_cast(h2_t, b), c, false);
#else
    h2_t ha = __builtin_bit_cast(h2_t, a), hb = __builtin_bit_cast(h2_t, b);
    return c + (float)ha.x * (float)hb.x + (float)ha.y * (float)hb.y;
#endif
}
__device__ __forceinline__ float fast_sigmoid(float x) {
    float e = __builtin_amdgcn_exp2f(-1.4426950408889634f * x);
    return __builtin_amdgcn_rcpf(1.f + e);
}
__device__ __forceinline__ float fast_tanh(float x) {
    float e = __builtin_amdgcn_exp2f(2.8853900817779268f * x);
    return 1.f - 2.f * __builtin_amdgcn_rcpf(e + 1.f);
}

#define MFMA16(a,b,c) __builtin_amdgcn_mfma_f32_16x16x32_bf16((a),(b),(c),0,0,0)

// ======================= prep kernels =======================
// x f32 [64][1024][256] -> bf16
__global__ void k_prep_x(const float* __restrict__ x, short* __restrict__ xb) {
    int i = (blockIdx.x * 256 + threadIdx.x) * 4;
    float4 v = *(const float4*)&x[i];
    short o[4] = { f2bs(v.x), f2bs(v.y), f2bs(v.z), f2bs(v.w) };
    *(uint2*)&xb[i] = *(uint2*)o;
}
// WkT[n][k] bf16, n in [0,1536): fwd cols then bwd cols
__global__ void k_prep_wk(const float* __restrict__ kf, const float* __restrict__ kb,
                          short* __restrict__ wkt) {
    int n = blockIdx.x, k = threadIdx.x;
    float v = (n < 768) ? kf[k * 768 + n] : kb[k * 768 + (n - 768)];
    wkt[n * 256 + k] = f2bs(v);
}
// recurrent weights packed f16-pairs: Wp[dir][gate][kc][j] (uint4 = k's 8kc..8kc+7)
__global__ void k_prep_wr(const float* __restrict__ wrf, const float* __restrict__ wrb,
                          uint4* __restrict__ wp) {
    int idx = blockIdx.x * 256 + threadIdx.x;          // 49152 total
    int dir = idx / 24576, rem = idx % 24576;
    int g = rem / 8192, rem2 = rem % 8192;
    int kc = rem2 / 256, j = rem2 % 256;
    int col = g * 256 + j;
    const float* w = dir ? wrb : wrf;
    uint c[4];
#pragma unroll
    for (int d = 0; d < 4; d++) {
        int k0 = kc * 8 + d * 2;
        uint lo = f16b(w[k0 * 768 + col]);
        uint hi = f16b(w[(k0 + 1) * 768 + col]);
        c[d] = lo | (hi << 16);
    }
    wp[idx] = make_uint4(c[0], c[1], c[2], c[3]);
}
// WbT_perm[kappa][e] bf16 ; kappa = k*256+n2 ; f = n2*7+k
__global__ void k_prep_wb(const float* __restrict__ wb, short* __restrict__ wbt) {
    int kp = blockIdx.x, e = threadIdx.x;
    int n2 = kp & 255, kk = kp >> 8;
    int f = n2 * 7 + kk;
    wbt[kp * 256 + e] = f2bs(wb[e * 1792 + f]);
}

// ======================= projection GEMM =======================
// [65536 x 256] @ [256 x 1536] -> xp f16 [dir][b][t][768] (+b[0], bwd time-reversed)
__global__ __launch_bounds__(512) void k_proj(const short* __restrict__ xb,
        const short* __restrict__ wkt, const float* __restrict__ gbf,
        const float* __restrict__ gbb, ushort_t* __restrict__ xp) {
    __shared__ union {
        struct { short A[128 * 40]; short B[128 * 40]; } st;
        ushort_t E[128 * 136];
    } u;
    int bid = blockIdx.x;
    int nt = bid % 12, mt = bid / 12;
    int r0 = mt * 128, n0 = nt * 128;
    int tid = threadIdx.x, lane = tid & 63, wid = tid >> 6;
    int wm = wid & 1, wn = wid >> 1;
    int q = lane >> 4, c = lane & 15;
    f32x4 acc[4][2];
#pragma unroll
    for (int mi = 0; mi < 4; mi++)
#pragma unroll
        for (int ni = 0; ni < 2; ni++) acc[mi][ni] = (f32x4){0.f, 0.f, 0.f, 0.f};
    int si = tid >> 2, sp = tid & 3;
    for (int kt = 0; kt < 8; kt++) {
        int k0 = kt * 32;
        *(uint4*)&u.st.A[si * 40 + sp * 8] = *(const uint4*)&xb[(r0 + si) * 256 + k0 + sp * 8];
        *(uint4*)&u.st.B[si * 40 + sp * 8] = *(const uint4*)&wkt[(n0 + si) * 256 + k0 + sp * 8];
        __syncthreads();
        bf16x8 af[4], bfr[2];
#pragma unroll
        for (int mi = 0; mi < 4; mi++) af[mi] = *(bf16x8*)&u.st.A[(wm * 64 + mi * 16 + c) * 40 + q * 8];
#pragma unroll
        for (int ni = 0; ni < 2; ni++) bfr[ni] = *(bf16x8*)&u.st.B[(wn * 32 + ni * 16 + c) * 40 + q * 8];
#pragma unroll
        for (int mi = 0; mi < 4; mi++)
#pragma unroll
            for (int ni = 0; ni < 2; ni++) acc[mi][ni] = MFMA16(af[mi], bfr[ni], acc[mi][ni]);
        __syncthreads();
    }
#pragma unroll
    for (int ni = 0; ni < 2; ni++) {
        int ng = n0 + wn * 32 + ni * 16 + c;
        bool d1 = ng >= 768; int nb = d1 ? ng - 768 : ng;
        float bias = d1 ? gbb[nb] : gbf[nb];
#pragma unroll
        for (int mi = 0; mi < 4; mi++)
#pragma unroll
            for (int v = 0; v < 4; v++) {
                int rl = wm * 64 + mi * 16 + q * 4 + v;
                u.E[rl * 136 + wn * 32 + ni * 16 + c] = f16b(acc[mi][ni][v] + bias);
            }
    }
    __syncthreads();
    {
        int i = tid >> 2, p = tid & 3;
        int r = r0 + i, b = r >> 10, t = r & 1023;
        int ng = n0 + p * 32;
        const ushort_t* src = &u.E[i * 136 + p * 32];
        ushort_t* dst;
        if (ng < 768) dst = xp + (size_t)(b * 1024 + t) * 768 + ng;
        else          dst = xp + 50331648ull + (size_t)(b * 1024 + (1023 - t)) * 768 + (ng - 768);
#pragma unroll
        for (int v = 0; v < 4; v++) *(uint4*)&dst[v * 8] = *(const uint4*)&src[v * 8];
    }
}

// ======================= GRU recurrence =======================
// 128 WGs x 512 thr: one (batch, dir) per CU, 8 waves (2/SIMD).
// K-half split within the wave (lanes l, l^32 share output j); 192 weight VGPRs.
// hc read in 4 chunks of 4 uint4 with 2-deep rotation + sched_barrier fences so
// peak live stays < 256 and weights remain arch-VGPR resident (R2: compiler
// hoisted all 16 ds_reads -> weights evicted to AGPR, VGPR_Count=116).
__global__ __launch_bounds__(512, 2) void k_gru(const uint4* __restrict__ wp,
        const ushort_t* __restrict__ xp, const float* __restrict__ gbf,
        const float* __restrict__ gbb, float* __restrict__ cbuf) {
    int wg = blockIdx.x;
    int dir = wg >> 6, b = wg & 63;
    int tid = threadIdx.x;
    int lane = tid & 63, w = tid >> 6;
    int half = lane >> 5;
    int j = w * 32 + (lane & 31);
    const uint4* W = wp + dir * 24576 + half * 4096 + j;   // half*16 kc-rows
    uint4 wz[16], wr[16], wn[16];
#pragma unroll
    for (int kc = 0; kc < 16; kc++) {
        wz[kc] = W[kc * 256];
        wr[kc] = W[8192 + kc * 256];
        wn[kc] = W[16384 + kc * 256];
    }
    __shared__ uint4 hbuf[2][32];
    const float* bs = (dir ? gbb : gbf) + 768 + j;   // b[1] row
    float bz = bs[0], br = bs[256], bn = bs[512];
    const ushort_t* X = xp + ((size_t)dir * 64 + b) * 786432 + j;
    ushort_t uz = X[0], ur = X[256], un = X[512];
    const ushort_t* Xn = X + 768;
    float h = 0.f;
    if (tid < 32) hbuf[0][tid] = (uint4){0, 0, 0, 0};
    __syncthreads();
#pragma unroll 1
    for (int tt = 0; tt < 1024; tt++) {
        const uint4* hb = &hbuf[tt & 1][half * 16];
        ushort_t nz = Xn[0], nr = Xn[256], nn = Xn[512];   // prefetch step tt+1
        Xn += 768;
        float az = 0.f, ar = 0.f, an = 0.f;
        uint4 c0 = hb[0], c1 = hb[1], c2 = hb[2], c3 = hb[3];
#pragma unroll
        for (int ch = 0; ch < 4; ch++) {
            uint4 n0, n1, n2, n3;
            if (ch < 3) {
                n0 = hb[ch * 4 + 4]; n1 = hb[ch * 4 + 5];
                n2 = hb[ch * 4 + 6]; n3 = hb[ch * 4 + 7];
            }
            int kb = ch * 4;
#define DOT1(hc, kk)                                                              \
            az = fdot2a(hc.x, wz[kk].x, az); ar = fdot2a(hc.x, wr[kk].x, ar);     \
            an = fdot2a(hc.x, wn[kk].x, an);                                      \
            az = fdot2a(hc.y, wz[kk].y, az); ar = fdot2a(hc.y, wr[kk].y, ar);     \
            an = fdot2a(hc.y, wn[kk].y, an);                                      \
            az = fdot2a(hc.z, wz[kk].z, az); ar = fdot2a(hc.z, wr[kk].z, ar);     \
            an = fdot2a(hc.z, wn[kk].z, an);                                      \
            az = fdot2a(hc.w, wz[kk].w, az); ar = fdot2a(hc.w, wr[kk].w, ar);     \
            an = fdot2a(hc.w, wn[kk].w, an);
            DOT1(c0, kb + 0) DOT1(c1, kb + 1) DOT1(c2, kb + 2) DOT1(c3, kb + 3)
#undef DOT1
            __builtin_amdgcn_sched_barrier(0);
            if (ch < 3) { c0 = n0; c1 = n1; c2 = n2; c3 = n3; }
        }
        az += __shfl_xor(az, 32, 64);
        ar += __shfl_xor(ar, 32, 64);
        an += __shfl_xor(an, 32, 64);
        float z = fast_sigmoid(h2f(uz) + az + bz);
        float r = fast_sigmoid(h2f(ur) + ar + br);
        float hh = fast_tanh(h2f(un) + r * (an + bn));
        h = z * h + (1.f - z) * hh;
        uz = nz; ur = nr; un = nn;
        if (half == 0) ((ushort_t*)&hbuf[(tt & 1) ^ 1][0])[j] = f16b(h);
        __syncthreads();
    }
    if (half == 0) cbuf[b * 512 + dir * 256 + j] = h;     // c = [hf | hb]
}

// ======================= hyper1: a = c @ Wa =======================
// [64 x 512] @ [512 x 65536] -> a bf16 [64][65536]
__global__ __launch_bounds__(256) void k_hyper1(const float* __restrict__ cbuf,
        const float* __restrict__ Wa, short* __restrict__ aout) {
    __shared__ union {
        struct { short A[64 * 40]; short B[128 * 40]; } st;
        ushort_t E[64 * 136];
    } u;
    int nt = blockIdx.x, n0 = nt * 128;
    int tid = threadIdx.x, lane = tid & 63, wid = tid >> 6;  // 4 waves, wave-tile 64x32
    int q = lane >> 4, c = lane & 15;
    f32x4 acc[4][2];
#pragma unroll
    for (int mi = 0; mi < 4; mi++)
#pragma unroll
        for (int ni = 0; ni < 2; ni++) acc[mi][ni] = (f32x4){0.f, 0.f, 0.f, 0.f};
    for (int kt = 0; kt < 16; kt++) {
        int k0 = kt * 32;
        {   // A 64x32 from cbuf f32 -> bf16
            int i = tid >> 2, p = tid & 3;
            const float* s = &cbuf[i * 512 + k0 + p * 8];
            short tmp[8];
#pragma unroll
            for (int v = 0; v < 8; v++) tmp[v] = f2bs(s[v]);
            *(uint4*)&u.st.A[i * 40 + p * 8] = *(uint4*)tmp;
        }
        {   // B: Wa[k][n] -> LDS [n][k] transposed
            int kk = tid >> 3, nn0 = (tid & 7) * 16;
            const float* s = &Wa[(size_t)(k0 + kk) * 65536 + n0 + nn0];
#pragma unroll
            for (int l = 0; l < 16; l++) u.st.B[(nn0 + l) * 40 + kk] = f2bs(s[l]);
        }
        __syncthreads();
        bf16x8 af[4], bfr[2];
#pragma unroll
        for (int mi = 0; mi < 4; mi++) af[mi] = *(bf16x8*)&u.st.A[(mi * 16 + c) * 40 + q * 8];
#pragma unroll
        for (int ni = 0; ni < 2; ni++) bfr[ni] = *(bf16x8*)&u.st.B[(wid * 32 + ni * 16 + c) * 40 + q * 8];
#pragma unroll
        for (int mi = 0; mi < 4; mi++)
#pragma unroll
            for (int ni = 0; ni < 2; ni++) acc[mi][ni] = MFMA16(af[mi], bfr[ni], acc[mi][ni]);
        __syncthreads();
    }
#pragma unroll
    for (int ni = 0; ni < 2; ni++)
#pragma unroll
        for (int mi = 0; mi < 4; mi++)
#pragma unroll
            for (int v = 0; v < 4; v++)
                u.E[(mi * 16 + q * 4 + v) * 136 + wid * 32 + ni * 16 + c] =
                    (ushort_t)f2bs(acc[mi][ni][v]);
    __syncthreads();
    {
        int i = tid >> 2, p = tid & 3;
        short* dst = aout + (size_t)i * 65536 + n0 + p * 32;
        const ushort_t* src = &u.E[i * 136 + p * 32];
#pragma unroll
        for (int v = 0; v < 4; v++) *(uint4*)&dst[v * 8] = *(const uint4*)&src[v * 8];
    }
}

// ======================= hyper2: fb = a @ WbT_perm =======================
// [16384 x 256] @ [256 x 1792] -> WconvT bf16 [b][co][kappa]
__global__ __launch_bounds__(512) void k_hyper2(const short* __restrict__ a,
        const short* __restrict__ wbt, short* __restrict__ wc) {
    __shared__ union {
        struct { short A[128 * 40]; short B[128 * 40]; } st;
        ushort_t E[128 * 136];
    } u;
    int bid = blockIdx.x;
    int nt = bid % 14, mt = bid / 14;
    int r0 = mt * 128, n0 = nt * 128;
    int tid = threadIdx.x, lane = tid & 63, wid = tid >> 6;
    int wm = wid & 1, wn = wid >> 1;
    int q = lane >> 4, c = lane & 15;
    f32x4 acc[4][2];
#pragma unroll
    for (int mi = 0; mi < 4; mi++)
#pragma unroll
        for (int ni = 0; ni < 2; ni++) acc[mi][ni] = (f32x4){0.f, 0.f, 0.f, 0.f};
    int si = tid >> 2, sp = tid & 3;
    for (int kt = 0; kt < 8; kt++) {
        int k0 = kt * 32;
        *(uint4*)&u.st.A[si * 40 + sp * 8] = *(const uint4*)&a[(r0 + si) * 256 + k0 + sp * 8];
        *(uint4*)&u.st.B[si * 40 + sp * 8] = *(const uint4*)&wbt[(n0 + si) * 256 + k0 + sp * 8];
        __syncthreads();
        bf16x8 af[4], bfr[2];
#pragma unroll
        for (int mi = 0; mi < 4; mi++) af[mi] = *(bf16x8*)&u.st.A[(wm * 64 + mi * 16 + c) * 40 + q * 8];
#pragma unroll
        for (int ni = 0; ni < 2; ni++) bfr[ni] = *(bf16x8*)&u.st.B[(wn * 32 + ni * 16 + c) * 40 + q * 8];
#pragma unroll
        for (int mi = 0; mi < 4; mi++)
#pragma unroll
            for (int ni = 0; ni < 2; ni++) acc[mi][ni] = MFMA16(af[mi], bfr[ni], acc[mi][ni]);
        __syncthreads();
    }
#pragma unroll
    for (int ni = 0; ni < 2; ni++)
#pragma unroll
        for (int mi = 0; mi < 4; mi++)
#pragma unroll
            for (int v = 0; v < 4; v++)
                u.E[(wm * 64 + mi * 16 + q * 4 + v) * 136 + wn * 32 + ni * 16 + c] =
                    (ushort_t)f2bs(acc[mi][ni][v]);
    __syncthreads();
    {
        int i = tid >> 2, p = tid & 3;
        int r = r0 + i, b = r >> 8, co = r & 255;
        short* dst = wc + (size_t)(b * 256 + co) * 1792 + n0 + p * 32;
        const ushort_t* src = &u.E[i * 136 + p * 32];
#pragma unroll
        for (int v = 0; v < 4; v++) *(uint4*)&dst[v * 8] = *(const uint4*)&src[v * 8];
    }
}

// ======================= per-sample conv + relu + maxpool =======================
// per b: [1024 x 1792] @ [1792 x 256]; A[s][kappa=k*256+ci] = x[b][s+k-3][ci]
__global__ __launch_bounds__(512) void k_conv(const short* __restrict__ xb,
        const short* __restrict__ wc, const float* __restrict__ cbias,
        float* __restrict__ out) {
    __shared__ union {
        struct { short A[128 * 72]; short B[256 * 72]; } st;
        ushort_t Y[128 * 256];
    } u;
    int bid = blockIdx.x;
    int bb = bid & 63, mt = bid >> 6;        // bid = mt*64+b : all mt of b on same XCD
    int s0 = mt * 126, p0 = mt * 42;
    int tid = threadIdx.x, lane = tid & 63, wid = tid >> 6;
    int wm = wid & 1, wn = wid >> 1;
    int q = lane >> 4, c = lane & 15;
    const short* xbb = xb + (size_t)bb * 262144;
    const short* wcb = wc + (size_t)bb * 458752;
    f32x4 acc[4][4];
#pragma unroll
    for (int mi = 0; mi < 4; mi++)
#pragma unroll
        for (int ni = 0; ni < 4; ni++) acc[mi][ni] = (f32x4){0.f, 0.f, 0.f, 0.f};
    for (int kc = 0; kc < 28; kc++) {
        int k = kc >> 2, c0 = (kc & 3) * 64;
        {   // A stage 128 x 64 (shifted x rows, zero-padded)
            int i = tid >> 2, p = tid & 3;
            int rs = s0 + i + k - 3;
            uint4 v0 = {0, 0, 0, 0}, v1 = {0, 0, 0, 0};
            if (rs >= 0 && rs < 1024) {
                const uint4* s = (const uint4*)&xbb[rs * 256 + c0 + p * 16];
                v0 = s[0]; v1 = s[1];
            }
            uint4* d = (uint4*)&u.st.A[i * 72 + p * 16];
            d[0] = v0; d[1] = v1;
        }
        {   // B stage 256co x 64kappa from WconvT[b][co][kappa]
            int co = tid >> 1, p = tid & 1;
            const uint4* s = (const uint4*)&wcb[co * 1792 + kc * 64 + p * 32];
            uint4* d = (uint4*)&u.st.B[co * 72 + p * 32];
            d[0] = s[0]; d[1] = s[1]; d[2] = s[2]; d[3] = s[3];
        }
        __syncthreads();
        bf16x8 af[4][2], bfr[4][2];
#pragma unroll
        for (int mi = 0; mi < 4; mi++)
#pragma unroll
            for (int kt = 0; kt < 2; kt++)
                af[mi][kt] = *(bf16x8*)&u.st.A[(wm * 64 + mi * 16 + c) * 72 + kt * 32 + q * 8];
#pragma unroll
        for (int ni = 0; ni < 4; ni++)
#pragma unroll
            for (int kt = 0; kt < 2; kt++)
                bfr[ni][kt] = *(bf16x8*)&u.st.B[(wn * 64 + ni * 16 + c) * 72 + kt * 32 + q * 8];
#pragma unroll
        for (int kt = 0; kt < 2; kt++)
#pragma unroll
            for (int mi = 0; mi < 4; mi++)
#pragma unroll
                for (int ni = 0; ni < 4; ni++)
                    acc[mi][ni] = MFMA16(af[mi][kt], bfr[ni][kt], acc[mi][ni]);
        __syncthreads();
    }
    // epilogue: +bias, relu, stage f16 y-tile
#pragma unroll
    for (int ni = 0; ni < 4; ni++) {
        int cg = wn * 64 + ni * 16 + c;
        float bias = cbias[cg];
#pragma unroll
        for (int mi = 0; mi < 4; mi++)
#pragma unroll
            for (int v = 0; v < 4; v++) {
                int rl = wm * 64 + mi * 16 + q * 4 + v;
                float val = acc[mi][ni][v] + bias;
                u.Y[rl * 256 + cg] = f16b(fmaxf(val, 0.f));
            }
    }
    __syncthreads();
    // maxpool(3): 42 pools x 256 channels
    for (int it = 0; it < 21; it++) {
        int idx = it * 512 + tid;
        int pp = idx >> 8, co = idx & 255;
        int p = p0 + pp;
        if (p < 341) {
            float a0 = h2f(u.Y[(3 * pp) * 256 + co]);
            float a1 = h2f(u.Y[(3 * pp + 1) * 256 + co]);
            float a2 = h2f(u.Y[(3 * pp + 2) * 256 + co]);
            out[(size_t)(bb * 341 + p) * 256 + co] = fmaxf(fmaxf(a0, a1), a2);
        }
    }
}

// ======================= launcher =======================
extern "C" void kernel_launch(void* const* d_in, const int* in_sizes, int n_in,
                              void* d_out, int out_size, void* d_ws, size_t ws_size,
                              hipStream_t stream) {
    const float* x    = (const float*)d_in[0];
    const float* gkf  = (const float*)d_in[2];
    const float* grf  = (const float*)d_in[3];
    const float* gbf  = (const float*)d_in[4];
    const float* gkb  = (const float*)d_in[5];
    const float* grb  = (const float*)d_in[6];
    const float* gbb  = (const float*)d_in[7];
    const float* Wa   = (const float*)d_in[8];
    const float* Wb   = (const float*)d_in[9];
    const float* cbias= (const float*)d_in[10];
    float* out = (float*)d_out;
    char* ws = (char*)d_ws;

    short*    xb   = (short*)(ws);                      // 33,554,432 B
    ushort_t* xp   = (ushort_t*)(ws + 33554432);        // 201,326,592 B (f+b, f16)
    short*    wkt  = (short*)(ws + 234881024);          // 786,432 B
    uint4*    wp   = (uint4*)(ws + 235667456);          // 786,432 B
    short*    wbt  = (short*)(ws + 236453888);          // 917,504 B
    float*    cbuf = (float*)(ws + 237371392);          // 131,072 B
    short*    aout = (short*)(ws + 237502464);          // 8,388,608 B
    short*    wc   = (short*)(ws + 245891072);          // 58,720,256 B  (end ~304.6 MB)

    hipLaunchKernelGGL(k_prep_x,  dim3(16384), dim3(256), 0, stream, x, xb);
    hipLaunchKernelGGL(k_prep_wk, dim3(1536),  dim3(256), 0, stream, gkf, gkb, wkt);
    hipLaunchKernelGGL(k_prep_wr, dim3(192),   dim3(256), 0, stream, grf, grb, wp);
    hipLaunchKernelGGL(k_prep_wb, dim3(1792),  dim3(256), 0, stream, Wb, wbt);
    hipLaunchKernelGGL(k_proj,    dim3(6144),  dim3(512), 0, stream, xb, wkt, gbf, gbb, xp);
    hipLaunchKernelGGL(k_gru,     dim3(128),   dim3(512), 0, stream, wp, xp, gbf, gbb, cbuf);
    hipLaunchKernelGGL(k_hyper1,  dim3(512),   dim3(256), 0, stream, cbuf, Wa, aout);
    hipLaunchKernelGGL(k_hyper2,  dim3(1792),  dim3(512), 0, stream, aout, wbt, wc);
    hipLaunchKernelGGL(k_conv,    dim3(576),   dim3(512), 0, stream, xb, wc, cbias, out);
}